// Round 4
// baseline (396.035 us; speedup 1.0000x reference)
//
#include <hip/hip_runtime.h>
#include <cstdint>
#include <cstddef>

#define B_ 4
#define S_ 2048
#define D_ 1024
#define H_ 16

typedef unsigned short u16;
typedef unsigned int u32;
typedef __attribute__((ext_vector_type(8))) short bf16x8;
typedef __attribute__((ext_vector_type(4))) float f32x4;

__device__ __forceinline__ u16 f2bf(float f) {
  union { float f; u32 u; } x; x.f = f;
  u32 r = x.u + 0x7fffu + ((x.u >> 16) & 1u);
  return (u16)(r >> 16);
}

__device__ __forceinline__ f32x4 mfma16(bf16x8 a, bf16x8 b, f32x4 c) {
  return __builtin_amdgcn_mfma_f32_16x16x32_bf16(a, b, c, 0, 0, 0);
}

// global->LDS direct copy, 16B per lane. LDS dest is wave-uniform base
// (HW adds lane*16); global src is per-lane (pre-swizzled for bank-free reads).
__device__ __forceinline__ void gload_lds16(const u16* g, u16* l) {
  __builtin_amdgcn_global_load_lds((const __attribute__((address_space(1))) void*)g,
                                   (__attribute__((address_space(3))) void*)l,
                                   16, 0, 0);
}

// ---------------- fp32 -> bf16 conversion (memory-bound pre-pass) -------------
__global__ __launch_bounds__(256) void cvt_kernel(const float4* __restrict__ src,
                                                  uint2* __restrict__ dst, int n4) {
  int i = blockIdx.x * 256 + threadIdx.x;
  if (i < n4) {
    float4 v = src[i];
    uint2 o;
    o.x = (u32)f2bf(v.x) | ((u32)f2bf(v.y) << 16);
    o.y = (u32)f2bf(v.z) | ((u32)f2bf(v.w) << 16);
    dst[i] = o;
  }
}

// ---------------- fused QKV projection: C[8192x3072] = A * B^T ---------------
// A: [8192x1024] bf16 K-major, Bm: [3072x1024] bf16 K-major (wq;wk;wv rows).
// Epilogue: +bias, Q scaled by 0.125, scatter to q/k [B,H,S,HD] and vT [B,H,HD,S].
__global__ __launch_bounds__(256) void qkv_gemm(
    const u16* __restrict__ A, const u16* __restrict__ Bm,
    const float* __restrict__ bq, const float* __restrict__ bk,
    const float* __restrict__ bv,
    u16* __restrict__ qbuf, u16* __restrict__ kbuf, u16* __restrict__ vtbuf)
{
  __shared__ __align__(16) u16 lA[128 * 64];
  __shared__ __align__(16) u16 lB[128 * 64];

  const int bid = blockIdx.x;
  const int wg = ((bid & 7) * 192) + (bid >> 3);   // XCD swizzle (1536 % 8 == 0)
  const int bm = wg & 63;                          // 64 M-blocks
  const int bn = wg >> 6;                          // 24 N-blocks
  const int tid = threadIdx.x;
  const int wid = tid >> 6, lane = tid & 63;
  const int g = lane >> 4, c = lane & 15;
  const int wm = wid & 1, wn = wid >> 1;
  const int lrow = lane >> 3;                      // 0..7
  const int lcb = (lane & 7) ^ lrow;               // pre-swizzled global col-block

  f32x4 acc[4][4];
#pragma unroll
  for (int i = 0; i < 4; ++i)
#pragma unroll
    for (int j = 0; j < 4; ++j) acc[i][j] = (f32x4)0.0f;

  const u16* Ab = A + (size_t)(bm * 128) * 1024;
  const u16* Bb = Bm + (size_t)(bn * 128) * 1024;

  for (int kt = 0; kt < 16; ++kt) {
    const int k0 = kt * 64;
#pragma unroll
    for (int jj = 0; jj < 4; ++jj) {
      const int r0 = wid * 32 + jj * 8;            // wave-uniform row chunk
      gload_lds16(Ab + (size_t)(r0 + lrow) * 1024 + k0 + lcb * 8, lA + r0 * 64);
      gload_lds16(Bb + (size_t)(r0 + lrow) * 1024 + k0 + lcb * 8, lB + r0 * 64);
    }
    __syncthreads();
#pragma unroll
    for (int ks = 0; ks < 2; ++ks) {
      bf16x8 af[4], bfv[4];
#pragma unroll
      for (int mi = 0; mi < 4; ++mi) {
        const int row = wm * 64 + mi * 16 + c;
        const int cb = (ks * 4 + g) ^ (c & 7);     // XOR de-swizzle on read
        af[mi] = *(const bf16x8*)(lA + row * 64 + cb * 8);
      }
#pragma unroll
      for (int ni = 0; ni < 4; ++ni) {
        const int row = wn * 64 + ni * 16 + c;
        const int cb = (ks * 4 + g) ^ (c & 7);
        bfv[ni] = *(const bf16x8*)(lB + row * 64 + cb * 8);
      }
#pragma unroll
      for (int mi = 0; mi < 4; ++mi)
#pragma unroll
        for (int ni = 0; ni < 4; ++ni)
          acc[mi][ni] = mfma16(af[mi], bfv[ni], acc[mi][ni]);
    }
    __syncthreads();
  }

  const int m0 = bm * 128 + wm * 64;
  const int n0 = bn * 128 + wn * 64;
#pragma unroll
  for (int ni = 0; ni < 4; ++ni) {
    const int col = n0 + ni * 16 + c;              // which-projection is wave-uniform
    const int which = col >> 10;
    const int d = col & 1023;
    const int hh = d >> 6, hd = d & 63;
    const float* bp = (which == 0) ? bq : (which == 1) ? bk : bv;
    const float bias = bp[d];
#pragma unroll
    for (int mi = 0; mi < 4; ++mi) {
#pragma unroll
      for (int r = 0; r < 4; ++r) {
        const int row = m0 + mi * 16 + g * 4 + r;  // C/D: col=lane&15, row=4*(lane>>4)+r
        const int bb = row >> 11, ss = row & 2047;
        float val = acc[mi][ni][r] + bias;
        if (which == 0) {
          val *= 0.125f;                           // fold 1/sqrt(64) into Q
          qbuf[((size_t)(bb * 16 + hh) * 2048 + ss) * 64 + hd] = f2bf(val);
        } else if (which == 1) {
          kbuf[((size_t)(bb * 16 + hh) * 2048 + ss) * 64 + hd] = f2bf(val);
        } else {
          vtbuf[((size_t)(bb * 16 + hh) * 64 + hd) * 2048 + ss] = f2bf(val);
        }
      }
    }
  }
}

// ---------------- flash attention: 4 waves x 32 q-rows, KV tiles of 64 --------
__global__ __launch_bounds__(256) void attn_kernel(
    const u16* __restrict__ qbuf, const u16* __restrict__ kbuf,
    const u16* __restrict__ vtbuf, const float* __restrict__ pad,
    float* __restrict__ out)
{
  __shared__ __align__(16) u16 lK[64 * 64];        // K tile [kv][hd], swizzled
  __shared__ __align__(16) u16 lV[64 * 64];        // V^T tile [hd][kv], swizzled
  __shared__ __align__(16) u16 lP[4 * 32 * 64];    // per-wave P [q][kv], swizzled
  __shared__ __align__(16) float lMask[64];

  const int bid = blockIdx.x;
  const int wg = ((bid & 7) << 7) | (bid >> 3);    // XCD swizzle: same (b,h) co-XCD
  const int bh = wg >> 4;
  const int qb = wg & 15;
  const int b = bh >> 4;
  const int h = bh & 15;
  const int tid = threadIdx.x;
  const int wid = tid >> 6, lane = tid & 63;
  const int g = lane >> 4, c = lane & 15;
  const int q0 = qb * 128 + wid * 32;

  const u16* qp = qbuf + (size_t)bh * S_ * 64;
  const u16* kp = kbuf + (size_t)bh * S_ * 64;
  const u16* vp = vtbuf + (size_t)bh * 64 * S_;

  // Q fragments in registers (scale already folded in); also serve as MFMA B-operand.
  bf16x8 qf[2][2];
#pragma unroll
  for (int nt = 0; nt < 2; ++nt)
#pragma unroll
    for (int ks = 0; ks < 2; ++ks)
      qf[nt][ks] = *(const bf16x8*)(qp + (size_t)(q0 + nt * 16 + c) * 64 + ks * 32 + g * 8);

  f32x4 o[2][4];
#pragma unroll
  for (int mi = 0; mi < 2; ++mi)
#pragma unroll
    for (int nh = 0; nh < 4; ++nh) o[mi][nh] = (f32x4)0.0f;

  float mst[2] = {-3e38f, -3e38f};
  float lst[2] = {0.0f, 0.0f};

  const int lrow = lane >> 3;
  const int lcb = (lane & 7) ^ lrow;
  u16* lPw = lP + wid * (32 * 64);

  for (int j = 0; j < 32; ++j) {
    const int kv0 = j * 64;
#pragma unroll
    for (int jj = 0; jj < 2; ++jj) {
      const int r0 = wid * 16 + jj * 8;
      gload_lds16(kp + (size_t)(kv0 + r0 + lrow) * 64 + lcb * 8, lK + r0 * 64);
      gload_lds16(vp + (size_t)(r0 + lrow) * 2048 + kv0 + lcb * 8, lV + r0 * 64);
    }
    if (tid < 64) lMask[tid] = (1.0f - pad[b * S_ + kv0 + tid]) * (-1e9f);
    __syncthreads();

    // Swapped QK^T: St[kv][q] = K . Q  (per-lane: q = 16*nt + c, kv = 16*mt + 4g + r)
    f32x4 st[4][2];
#pragma unroll
    for (int mt = 0; mt < 4; ++mt) { st[mt][0] = (f32x4)0.0f; st[mt][1] = (f32x4)0.0f; }
#pragma unroll
    for (int ks = 0; ks < 2; ++ks) {
#pragma unroll
      for (int mt = 0; mt < 4; ++mt) {
        const int row = mt * 16 + c;
        const int cb = (ks * 4 + g) ^ (c & 7);
        const bf16x8 kf = *(const bf16x8*)(lK + row * 64 + cb * 8);
        st[mt][0] = mfma16(kf, qf[0][ks], st[mt][0]);
        st[mt][1] = mfma16(kf, qf[1][ks], st[mt][1]);
      }
    }

    // additive pad-mask bias per kv row (broadcast reads, vectorized)
    float mb[4][4];
#pragma unroll
    for (int mt = 0; mt < 4; ++mt) {
      const float4 m4 = *(const float4*)&lMask[mt * 16 + g * 4];
      mb[mt][0] = m4.x; mb[mt][1] = m4.y; mb[mt][2] = m4.z; mb[mt][3] = m4.w;
    }

#pragma unroll
    for (int nt = 0; nt < 2; ++nt) {
      float tmax = -3e38f;
#pragma unroll
      for (int mt = 0; mt < 4; ++mt)
#pragma unroll
        for (int r = 0; r < 4; ++r) {
          st[mt][nt][r] += mb[mt][r];
          tmax = fmaxf(tmax, st[mt][nt][r]);
        }
      tmax = fmaxf(tmax, __shfl_xor(tmax, 16));
      tmax = fmaxf(tmax, __shfl_xor(tmax, 32));
      const float mnew = fmaxf(mst[nt], tmax);
      const float fac = exp2f((mst[nt] - mnew) * 1.44269504f);
      mst[nt] = mnew;
      float rsum = 0.0f;
#pragma unroll
      for (int mt = 0; mt < 4; ++mt)
#pragma unroll
        for (int r = 0; r < 4; ++r) {
          const float p = exp2f((st[mt][nt][r] - mnew) * 1.44269504f);
          st[mt][nt][r] = p;
          rsum += p;
        }
      rsum += __shfl_xor(rsum, 16);
      rsum += __shfl_xor(rsum, 32);
      lst[nt] = lst[nt] * fac + rsum;

      // P -> LDS: 4 consecutive kv per reg -> packed ds_write_b64, XOR-swizzled
#pragma unroll
      for (int mt = 0; mt < 4; ++mt) {
        uint2 pk;
        pk.x = (u32)f2bf(st[mt][nt][0]) | ((u32)f2bf(st[mt][nt][1]) << 16);
        pk.y = (u32)f2bf(st[mt][nt][2]) | ((u32)f2bf(st[mt][nt][3]) << 16);
        const int rowq = nt * 16 + c;
        const int cb = (2 * mt + (g >> 1)) ^ (c & 7);
        *(uint2*)(lPw + rowq * 64 + cb * 8 + (g & 1) * 4) = pk;
      }

      // rescale running O (transpose-broadcast the factor to out layout)
#pragma unroll
      for (int r = 0; r < 4; ++r) {
        const float fr = __shfl(fac, g * 4 + r);
#pragma unroll
        for (int nh = 0; nh < 4; ++nh) o[nt][nh][r] *= fr;
      }
    }

    // PV: O[q][hd] += P[q][kv] * V[kv][hd]   (A = P from LDS, B = V^T from LDS)
#pragma unroll
    for (int ks = 0; ks < 2; ++ks) {
      bf16x8 pa[2];
#pragma unroll
      for (int mi = 0; mi < 2; ++mi) {
        const int row = mi * 16 + c;
        const int cb = (ks * 4 + g) ^ (c & 7);
        pa[mi] = *(const bf16x8*)(lPw + row * 64 + cb * 8);
      }
#pragma unroll
      for (int nh = 0; nh < 4; ++nh) {
        const int row = nh * 16 + c;
        const int cb = (ks * 4 + g) ^ (c & 7);
        const bf16x8 vf = *(const bf16x8*)(lV + row * 64 + cb * 8);
#pragma unroll
        for (int mi = 0; mi < 2; ++mi)
          o[mi][nh] = mfma16(pa[mi], vf, o[mi][nh]);
      }
    }
    __syncthreads();
  }

  // finalize: divide by row sum, write [B,S,D] fp32
#pragma unroll
  for (int mi = 0; mi < 2; ++mi) {
#pragma unroll
    for (int r = 0; r < 4; ++r) {
      const float lr = __shfl(lst[mi], g * 4 + r);
      const float inv = 1.0f / lr;
      const int srow = q0 + mi * 16 + g * 4 + r;
      float* op = out + (size_t)(b * S_ + srow) * D_ + h * 64;
#pragma unroll
      for (int nh = 0; nh < 4; ++nh)
        op[nh * 16 + c] = o[mi][nh][r] * inv;
    }
  }
}

extern "C" void kernel_launch(void* const* d_in, const int* in_sizes, int n_in,
                              void* d_out, int out_size, void* d_ws, size_t ws_size,
                              hipStream_t stream) {
  const float* hs  = (const float*)d_in[0];
  const float* pad = (const float*)d_in[1];
  const float* wq  = (const float*)d_in[2];
  const float* bq  = (const float*)d_in[3];
  const float* wk  = (const float*)d_in[4];
  const float* bk  = (const float*)d_in[5];
  const float* wv  = (const float*)d_in[6];
  const float* bv  = (const float*)d_in[7];
  float* out = (float*)d_out;

  char* ws = (char*)d_ws;
  u16* Abf   = (u16*)ws;                    // 16 MB: hidden as bf16 [8192][1024]
  u16* Bbf   = (u16*)(ws + (16u << 20));    //  6 MB: [wq;wk;wv] bf16 [3072][1024]
  u16* qbuf  = (u16*)(ws + (22u << 20));    // 16 MB: Q bf16 [B,H,S,HD] (x0.125)
  u16* kbuf  = (u16*)(ws + (38u << 20));    // 16 MB: K bf16 [B,H,S,HD]
  u16* vtbuf = (u16*)(ws + (54u << 20));    // 16 MB: V^T bf16 [B,H,HD,S]

  cvt_kernel<<<8192, 256, 0, stream>>>((const float4*)hs, (uint2*)Abf, 2097152);
  cvt_kernel<<<1024, 256, 0, stream>>>((const float4*)wq, (uint2*)Bbf, 262144);
  cvt_kernel<<<1024, 256, 0, stream>>>((const float4*)wk, (uint2*)(Bbf + (1u << 20)), 262144);
  cvt_kernel<<<1024, 256, 0, stream>>>((const float4*)wv, (uint2*)(Bbf + (2u << 20)), 262144);

  qkv_gemm<<<1536, 256, 0, stream>>>(Abf, Bbf, bq, bk, bv, qbuf, kbuf, vtbuf);
  attn_kernel<<<1024, 256, 0, stream>>>(qbuf, kbuf, vtbuf, pad, out);
}

// Round 5
// 358.748 us; speedup vs baseline: 1.1039x; 1.1039x over previous
//
#include <hip/hip_runtime.h>
#include <cstdint>
#include <cstddef>

#define B_ 4
#define S_ 2048
#define D_ 1024
#define H_ 16

typedef unsigned short u16;
typedef unsigned int u32;
typedef __attribute__((ext_vector_type(8))) short bf16x8;
typedef __attribute__((ext_vector_type(4))) float f32x4;

__device__ __forceinline__ u16 f2bf(float f) {
  union { float f; u32 u; } x; x.f = f;
  u32 r = x.u + 0x7fffu + ((x.u >> 16) & 1u);
  return (u16)(r >> 16);
}

// packed fp32->bf16 pair (RTNE) — no builtin on gfx950, inline asm per T12
__device__ __forceinline__ u32 cvtpk_bf16(float lo, float hi) {
  u32 r;
  asm("v_cvt_pk_bf16_f32 %0, %1, %2" : "=v"(r) : "v"(lo), "v"(hi));
  return r;
}

__device__ __forceinline__ float max3f(float a, float b, float c) {
  return fmaxf(fmaxf(a, b), c);   // clang fuses to v_max3_f32
}

__device__ __forceinline__ f32x4 mfma16(bf16x8 a, bf16x8 b, f32x4 c) {
  return __builtin_amdgcn_mfma_f32_16x16x32_bf16(a, b, c, 0, 0, 0);
}

// global->LDS direct copy, 16B per lane. LDS dest is wave-uniform base
// (HW adds lane*16); global src is per-lane (pre-swizzled for bank-free reads).
__device__ __forceinline__ void gload_lds16(const u16* g, u16* l) {
  __builtin_amdgcn_global_load_lds((const __attribute__((address_space(1))) void*)g,
                                   (__attribute__((address_space(3))) void*)l,
                                   16, 0, 0);
}

// ---------------- fp32 -> bf16 conversion (memory-bound pre-pass) -------------
__global__ __launch_bounds__(256) void cvt_kernel(const float4* __restrict__ src,
                                                  uint2* __restrict__ dst, int n4) {
  int i = blockIdx.x * 256 + threadIdx.x;
  if (i < n4) {
    float4 v = src[i];
    uint2 o;
    o.x = cvtpk_bf16(v.x, v.y);
    o.y = cvtpk_bf16(v.z, v.w);
    dst[i] = o;
  }
}

// ---------------- fused QKV projection: C[8192x3072] = A * B^T ---------------
// A: [8192x1024] bf16 K-major, Bm: [3072x1024] bf16 K-major (wq;wk;wv rows).
// Epilogue: +bias, Q scaled by 0.125, scatter to q/k [B,H,S,HD] and vT [B,H,HD,S].
__global__ __launch_bounds__(256) void qkv_gemm(
    const u16* __restrict__ A, const u16* __restrict__ Bm,
    const float* __restrict__ bq, const float* __restrict__ bk,
    const float* __restrict__ bv,
    u16* __restrict__ qbuf, u16* __restrict__ kbuf, u16* __restrict__ vtbuf)
{
  __shared__ __align__(16) u16 lA[128 * 64];
  __shared__ __align__(16) u16 lB[128 * 64];

  const int bid = blockIdx.x;
  const int wg = ((bid & 7) * 192) + (bid >> 3);   // XCD swizzle (1536 % 8 == 0)
  const int bm = wg & 63;                          // 64 M-blocks
  const int bn = wg >> 6;                          // 24 N-blocks
  const int tid = threadIdx.x;
  const int wid = tid >> 6, lane = tid & 63;
  const int g = lane >> 4, c = lane & 15;
  const int wm = wid & 1, wn = wid >> 1;
  const int lrow = lane >> 3;                      // 0..7
  const int lcb = (lane & 7) ^ lrow;               // pre-swizzled global col-block

  f32x4 acc[4][4];
#pragma unroll
  for (int i = 0; i < 4; ++i)
#pragma unroll
    for (int j = 0; j < 4; ++j) acc[i][j] = (f32x4)0.0f;

  const u16* Ab = A + (size_t)(bm * 128) * 1024;
  const u16* Bb = Bm + (size_t)(bn * 128) * 1024;

  for (int kt = 0; kt < 16; ++kt) {
    const int k0 = kt * 64;
#pragma unroll
    for (int jj = 0; jj < 4; ++jj) {
      const int r0 = wid * 32 + jj * 8;            // wave-uniform row chunk
      gload_lds16(Ab + (size_t)(r0 + lrow) * 1024 + k0 + lcb * 8, lA + r0 * 64);
      gload_lds16(Bb + (size_t)(r0 + lrow) * 1024 + k0 + lcb * 8, lB + r0 * 64);
    }
    __syncthreads();
#pragma unroll
    for (int ks = 0; ks < 2; ++ks) {
      bf16x8 af[4], bfv[4];
#pragma unroll
      for (int mi = 0; mi < 4; ++mi) {
        const int row = wm * 64 + mi * 16 + c;
        const int cb = (ks * 4 + g) ^ (c & 7);     // XOR de-swizzle on read
        af[mi] = *(const bf16x8*)(lA + row * 64 + cb * 8);
      }
#pragma unroll
      for (int ni = 0; ni < 4; ++ni) {
        const int row = wn * 64 + ni * 16 + c;
        const int cb = (ks * 4 + g) ^ (c & 7);
        bfv[ni] = *(const bf16x8*)(lB + row * 64 + cb * 8);
      }
#pragma unroll
      for (int mi = 0; mi < 4; ++mi)
#pragma unroll
        for (int ni = 0; ni < 4; ++ni)
          acc[mi][ni] = mfma16(af[mi], bfv[ni], acc[mi][ni]);
    }
    __syncthreads();
  }

  const int m0 = bm * 128 + wm * 64;
  const int n0 = bn * 128 + wn * 64;
#pragma unroll
  for (int ni = 0; ni < 4; ++ni) {
    const int col = n0 + ni * 16 + c;              // which-projection is wave-uniform
    const int which = col >> 10;
    const int d = col & 1023;
    const int hh = d >> 6, hd = d & 63;
    const float* bp = (which == 0) ? bq : (which == 1) ? bk : bv;
    const float bias = bp[d];
#pragma unroll
    for (int mi = 0; mi < 4; ++mi) {
#pragma unroll
      for (int r = 0; r < 4; ++r) {
        const int row = m0 + mi * 16 + g * 4 + r;  // C/D: col=lane&15, row=4*(lane>>4)+r
        const int bb = row >> 11, ss = row & 2047;
        float val = acc[mi][ni][r] + bias;
        if (which == 0) {
          val *= 0.125f;                           // fold 1/sqrt(64) into Q
          qbuf[((size_t)(bb * 16 + hh) * 2048 + ss) * 64 + hd] = f2bf(val);
        } else if (which == 1) {
          kbuf[((size_t)(bb * 16 + hh) * 2048 + ss) * 64 + hd] = f2bf(val);
        } else {
          vtbuf[((size_t)(bb * 16 + hh) * 64 + hd) * 2048 + ss] = f2bf(val);
        }
      }
    }
  }
}

// ---------------- flash attention: 4 waves x 32 q-rows, KV tiles of 64 --------
__global__ __launch_bounds__(256) void attn_kernel(
    const u16* __restrict__ qbuf, const u16* __restrict__ kbuf,
    const u16* __restrict__ vtbuf, const float* __restrict__ pad,
    float* __restrict__ out)
{
  __shared__ __align__(16) u16 lK[64 * 64];        // K tile [kv][hd], swizzled
  __shared__ __align__(16) u16 lV[64 * 64];        // V^T tile [hd][kv], swizzled
  __shared__ __align__(16) u16 lP[4 * 32 * 64];    // per-wave P [q][kv], swizzled
  __shared__ __align__(16) float lMask[64];

  const int bid = blockIdx.x;
  const int wg = ((bid & 7) << 7) | (bid >> 3);    // XCD swizzle: same (b,h) co-XCD
  const int bh = wg >> 4;
  const int qb = wg & 15;
  const int b = bh >> 4;
  const int h = bh & 15;
  const int tid = threadIdx.x;
  const int wid = tid >> 6, lane = tid & 63;
  const int g = lane >> 4, c = lane & 15;
  const int q0 = qb * 128 + wid * 32;

  const u16* qp = qbuf + (size_t)bh * S_ * 64;
  const u16* kp = kbuf + (size_t)bh * S_ * 64;
  const u16* vp = vtbuf + (size_t)bh * 64 * S_;

  // Q fragments in registers (scale already folded in); also serve as MFMA B-operand.
  bf16x8 qf[2][2];
#pragma unroll
  for (int nt = 0; nt < 2; ++nt)
#pragma unroll
    for (int ks = 0; ks < 2; ++ks)
      qf[nt][ks] = *(const bf16x8*)(qp + (size_t)(q0 + nt * 16 + c) * 64 + ks * 32 + g * 8);

  f32x4 o[2][4];
#pragma unroll
  for (int mi = 0; mi < 2; ++mi)
#pragma unroll
    for (int nh = 0; nh < 4; ++nh) o[mi][nh] = (f32x4)0.0f;

  float mst[2] = {-3e38f, -3e38f};
  float lst[2] = {0.0f, 0.0f};

  const int lrow = lane >> 3;
  const int lcb = (lane & 7) ^ lrow;
  u16* lPw = lP + wid * (32 * 64);
  const float LOG2E = 1.44269504f;

  for (int j = 0; j < 32; ++j) {
    const int kv0 = j * 64;
#pragma unroll
    for (int jj = 0; jj < 2; ++jj) {
      const int r0 = wid * 16 + jj * 8;
      gload_lds16(kp + (size_t)(kv0 + r0 + lrow) * 64 + lcb * 8, lK + r0 * 64);
      gload_lds16(vp + (size_t)(r0 + lrow) * 2048 + kv0 + lcb * 8, lV + r0 * 64);
    }
    if (tid < 64) lMask[tid] = (1.0f - pad[b * S_ + kv0 + tid]) * (-1e9f);
    __syncthreads();

    // Swapped QK^T: St[kv][q] = K . Q  (per-lane: q = 16*nt + c, kv = 16*mt + 4g + r)
    f32x4 st[4][2];
#pragma unroll
    for (int mt = 0; mt < 4; ++mt) { st[mt][0] = (f32x4)0.0f; st[mt][1] = (f32x4)0.0f; }
#pragma unroll
    for (int ks = 0; ks < 2; ++ks) {
#pragma unroll
      for (int mt = 0; mt < 4; ++mt) {
        const int row = mt * 16 + c;
        const int cb = (ks * 4 + g) ^ (c & 7);
        const bf16x8 kf = *(const bf16x8*)(lK + row * 64 + cb * 8);
        st[mt][0] = mfma16(kf, qf[0][ks], st[mt][0]);
        st[mt][1] = mfma16(kf, qf[1][ks], st[mt][1]);
      }
    }

    // additive pad-mask bias per kv row (broadcast reads, vectorized)
    float mb[4][4];
#pragma unroll
    for (int mt = 0; mt < 4; ++mt) {
      const float4 m4 = *(const float4*)&lMask[mt * 16 + g * 4];
      mb[mt][0] = m4.x; mb[mt][1] = m4.y; mb[mt][2] = m4.z; mb[mt][3] = m4.w;
    }

#pragma unroll
    for (int nt = 0; nt < 2; ++nt) {
      // mask add + row-max via max3 trees
      float sv[16];
#pragma unroll
      for (int mt = 0; mt < 4; ++mt)
#pragma unroll
        for (int r = 0; r < 4; ++r) {
          const float v = st[mt][nt][r] + mb[mt][r];
          st[mt][nt][r] = v;
          sv[mt * 4 + r] = v;
        }
      float tmax = max3f(sv[0], sv[1], sv[2]);
      tmax = max3f(tmax, sv[3], sv[4]);
      tmax = max3f(tmax, sv[5], sv[6]);
      tmax = max3f(tmax, sv[7], sv[8]);
      tmax = max3f(tmax, sv[9], sv[10]);
      tmax = max3f(tmax, sv[11], sv[12]);
      tmax = max3f(tmax, sv[13], sv[14]);
      tmax = fmaxf(tmax, sv[15]);
      tmax = fmaxf(tmax, __shfl_xor(tmax, 16));
      tmax = fmaxf(tmax, __shfl_xor(tmax, 32));

      // T13 defer-max: only rescale when the running max grows by > 8
      if (!__all(tmax - mst[nt] <= 8.0f)) {
        const float mnew = fmaxf(mst[nt], tmax);
        const float fac = exp2f((mst[nt] - mnew) * LOG2E);
        mst[nt] = mnew;
        lst[nt] *= fac;
#pragma unroll
        for (int r = 0; r < 4; ++r) {
          const float fr = __shfl(fac, g * 4 + r);
#pragma unroll
          for (int nh = 0; nh < 4; ++nh) o[nt][nh][r] *= fr;
        }
      }

      const float ml = mst[nt] * LOG2E;
      float rsum = 0.0f;
#pragma unroll
      for (int mt = 0; mt < 4; ++mt)
#pragma unroll
        for (int r = 0; r < 4; ++r) {
          const float p = exp2f(fmaf(st[mt][nt][r], LOG2E, -ml));
          st[mt][nt][r] = p;
          rsum += p;
        }
      rsum += __shfl_xor(rsum, 16);
      rsum += __shfl_xor(rsum, 32);
      lst[nt] += rsum;

      // P -> LDS: packed v_cvt_pk_bf16_f32 pairs -> ds_write_b64, XOR-swizzled
#pragma unroll
      for (int mt = 0; mt < 4; ++mt) {
        uint2 pk;
        pk.x = cvtpk_bf16(st[mt][nt][0], st[mt][nt][1]);
        pk.y = cvtpk_bf16(st[mt][nt][2], st[mt][nt][3]);
        const int rowq = nt * 16 + c;
        const int cb = (2 * mt + (g >> 1)) ^ (c & 7);
        *(uint2*)(lPw + rowq * 64 + cb * 8 + (g & 1) * 4) = pk;
      }
    }

    // PV: O[q][hd] += P[q][kv] * V[kv][hd]   (A = P from LDS, B = V^T from LDS)
#pragma unroll
    for (int ks = 0; ks < 2; ++ks) {
      bf16x8 pa[2];
#pragma unroll
      for (int mi = 0; mi < 2; ++mi) {
        const int row = mi * 16 + c;
        const int cb = (ks * 4 + g) ^ (c & 7);
        pa[mi] = *(const bf16x8*)(lPw + row * 64 + cb * 8);
      }
#pragma unroll
      for (int nh = 0; nh < 4; ++nh) {
        const int row = nh * 16 + c;
        const int cb = (ks * 4 + g) ^ (c & 7);
        const bf16x8 vf = *(const bf16x8*)(lV + row * 64 + cb * 8);
#pragma unroll
        for (int mi = 0; mi < 2; ++mi)
          o[mi][nh] = mfma16(pa[mi], vf, o[mi][nh]);
      }
    }
    __syncthreads();
  }

  // finalize: divide by row sum, write [B,S,D] fp32
#pragma unroll
  for (int mi = 0; mi < 2; ++mi) {
#pragma unroll
    for (int r = 0; r < 4; ++r) {
      const float lr = __shfl(lst[mi], g * 4 + r);
      const float inv = 1.0f / lr;
      const int srow = q0 + mi * 16 + g * 4 + r;
      float* op = out + (size_t)(b * S_ + srow) * D_ + h * 64;
#pragma unroll
      for (int nh = 0; nh < 4; ++nh)
        op[nh * 16 + c] = o[mi][nh][r] * inv;
    }
  }
}

extern "C" void kernel_launch(void* const* d_in, const int* in_sizes, int n_in,
                              void* d_out, int out_size, void* d_ws, size_t ws_size,
                              hipStream_t stream) {
  const float* hs  = (const float*)d_in[0];
  const float* pad = (const float*)d_in[1];
  const float* wq  = (const float*)d_in[2];
  const float* bq  = (const float*)d_in[3];
  const float* wk  = (const float*)d_in[4];
  const float* bk  = (const float*)d_in[5];
  const float* wv  = (const float*)d_in[6];
  const float* bv  = (const float*)d_in[7];
  float* out = (float*)d_out;

  char* ws = (char*)d_ws;
  u16* Abf   = (u16*)ws;                    // 16 MB: hidden as bf16 [8192][1024]
  u16* Bbf   = (u16*)(ws + (16u << 20));    //  6 MB: [wq;wk;wv] bf16 [3072][1024]
  u16* qbuf  = (u16*)(ws + (22u << 20));    // 16 MB: Q bf16 [B,H,S,HD] (x0.125)
  u16* kbuf  = (u16*)(ws + (38u << 20));    // 16 MB: K bf16 [B,H,S,HD]
  u16* vtbuf = (u16*)(ws + (54u << 20));    // 16 MB: V^T bf16 [B,H,HD,S]

  cvt_kernel<<<8192, 256, 0, stream>>>((const float4*)hs, (uint2*)Abf, 2097152);
  cvt_kernel<<<1024, 256, 0, stream>>>((const float4*)wq, (uint2*)Bbf, 262144);
  cvt_kernel<<<1024, 256, 0, stream>>>((const float4*)wk, (uint2*)(Bbf + (1u << 20)), 262144);
  cvt_kernel<<<1024, 256, 0, stream>>>((const float4*)wv, (uint2*)(Bbf + (2u << 20)), 262144);

  qkv_gemm<<<1536, 256, 0, stream>>>(Abf, Bbf, bq, bk, bv, qbuf, kbuf, vtbuf);
  attn_kernel<<<1024, 256, 0, stream>>>(qbuf, kbuf, vtbuf, pad, out);
}